// Round 9
// baseline (255.601 us; speedup 1.0000x reference)
//
#include <hip/hip_runtime.h>

// Problem constants
#define BB   2
#define NN   4096
#define CC   512
#define HH   8
#define DD   64
#define MR   8192          // B*N rows
#define NC3  1536          // 3*C
#define PS   4194304       // per-part stride in qkv buffer = B*H*N*D

typedef __attribute__((ext_vector_type(8))) short short8;
typedef __attribute__((ext_vector_type(4))) short short4v;
typedef __attribute__((ext_vector_type(4))) float floatx4;

// K=16 bf16 MFMA: B-layout B[k=quad*4+j][n=l16] == 16x16 C-layout -> P stays
// in registers between QK^T and PV.
#if __has_builtin(__builtin_amdgcn_mfma_f32_16x16x16_bf16_1k)
#define MFMA16(a, b, c) __builtin_amdgcn_mfma_f32_16x16x16_bf16_1k(a, b, c, 0, 0, 0)
#elif __has_builtin(__builtin_amdgcn_mfma_f32_16x16x16_bf16)
#define MFMA16(a, b, c) __builtin_amdgcn_mfma_f32_16x16x16_bf16(a, b, c, 0, 0, 0)
#else
__device__ inline floatx4 mfma16_asm(short4v a, short4v b, floatx4 c) {
  asm volatile("v_mfma_f32_16x16x16_bf16 %0, %1, %2, %0" : "+v"(c) : "v"(a), "v"(b));
  return c;
}
#define MFMA16(a, b, c) mfma16_asm(a, b, c)
#endif

__device__ inline unsigned short f2bf(float f) {
  unsigned int u = __float_as_uint(f);
  u = (u + 0x7fffu + ((u >> 16) & 1u)) >> 16;
  return (unsigned short)u;
}

__device__ inline unsigned int pack_bf2(float a, float b) {
  unsigned int ua = __float_as_uint(a) + 0x8000u;
  unsigned int ub = __float_as_uint(b) + 0x8000u;
  return (ub & 0xffff0000u) | (ua >> 16);
}

__device__ inline short4v pack_bf4(float a, float b, float c, float d) {
  union { unsigned int u[2]; short4v v; } t;
  t.u[0] = pack_bf2(a, b);
  t.u[1] = pack_bf2(c, d);
  return t.v;
}

__device__ inline floatx4 fzero4() { floatx4 z = {0.f, 0.f, 0.f, 0.f}; return z; }

__device__ inline void async_cp16(const void* g, void* l) {
  __builtin_amdgcn_global_load_lds(
      (const __attribute__((address_space(1))) unsigned int*)g,
      (__attribute__((address_space(3))) unsigned int*)l, 16, 0, 0);
}

// ---------------------------------------------------------------------------
// Kernel 0: convert + transpose w_qkv [512,1536] fp32 -> wt [1536,512] bf16.
// ---------------------------------------------------------------------------
__global__ __launch_bounds__(256) void convert_w_kernel(
    const float* __restrict__ w, unsigned short* __restrict__ wt) {
  __shared__ short T[64][68];
  int bn = blockIdx.x;                   // 0..23
  int bk = blockIdx.y;                   // 0..7
  int tid = threadIdx.x;
  for (int p = 0; p < 4; p++) {
    int k = p * 16 + (tid >> 4);
    int n4 = (tid & 15) * 4;
    float4 v = *(const float4*)&w[(size_t)(bk * 64 + k) * NC3 + bn * 64 + n4];
    T[n4 + 0][k] = (short)f2bf(v.x);
    T[n4 + 1][k] = (short)f2bf(v.y);
    T[n4 + 2][k] = (short)f2bf(v.z);
    T[n4 + 3][k] = (short)f2bf(v.w);
  }
  __syncthreads();
  for (int p = 0; p < 2; p++) {
    int n = p * 32 + (tid >> 3);
    int k8 = (tid & 7) * 8;
    uint4 v = *(uint4*)&T[n][k8];
    *(uint4*)&wt[(size_t)(bn * 64 + n) * 512 + bk * 64 + k8] = v;
  }
}

// ---------------------------------------------------------------------------
// Kernel 1: pre-LayerNorm, one wave per row, bf16 output only.
// ---------------------------------------------------------------------------
__global__ __launch_bounds__(256) void pre_ln_kernel(
    const float* __restrict__ x, const float* __restrict__ g,
    const float* __restrict__ be, unsigned short* __restrict__ xnb) {
  int wv = threadIdx.x >> 6, lane = threadIdx.x & 63;
  int row = blockIdx.x * 4 + wv;
  const float4* xr = (const float4*)(x + (size_t)row * CC);
  float4 v0 = xr[lane];
  float4 v1 = xr[64 + lane];
  float s  = (v0.x + v0.y) + (v0.z + v0.w) + (v1.x + v1.y) + (v1.z + v1.w);
  float sq = (v0.x * v0.x + v0.y * v0.y) + (v0.z * v0.z + v0.w * v0.w) +
             (v1.x * v1.x + v1.y * v1.y) + (v1.z * v1.z + v1.w * v1.w);
  for (int off = 1; off < 64; off <<= 1) {
    s  += __shfl_xor(s,  off, 64);
    sq += __shfl_xor(sq, off, 64);
  }
  float mean = s * (1.0f / CC);
  float var  = sq * (1.0f / CC) - mean * mean;
  float rstd = rsqrtf(var + 1e-5f);
  const float4* gg = (const float4*)g;
  const float4* bb = (const float4*)be;
  float4 g0 = gg[lane], g1 = gg[64 + lane];
  float4 b0 = bb[lane], b1 = bb[64 + lane];
  float4 o0, o1;
  o0.x = (v0.x - mean) * rstd * g0.x + b0.x;
  o0.y = (v0.y - mean) * rstd * g0.y + b0.y;
  o0.z = (v0.z - mean) * rstd * g0.z + b0.z;
  o0.w = (v0.w - mean) * rstd * g0.w + b0.w;
  o1.x = (v1.x - mean) * rstd * g1.x + b1.x;
  o1.y = (v1.y - mean) * rstd * g1.y + b1.y;
  o1.z = (v1.z - mean) * rstd * g1.z + b1.z;
  o1.w = (v1.w - mean) * rstd * g1.w + b1.w;
  size_t base = (size_t)row * CC;
  uint2 u0, u1;
  u0.x = pack_bf2(o0.x, o0.y); u0.y = pack_bf2(o0.z, o0.w);
  u1.x = pack_bf2(o1.x, o1.y); u1.y = pack_bf2(o1.z, o1.w);
  *(uint2*)&xnb[base + 4 * lane] = u0;
  *(uint2*)&xnb[base + 256 + 4 * lane] = u1;
}

// ---------------------------------------------------------------------------
// Kernel 2: QKV GEMM. SINGLE-buffered 32 KB LDS loop (34.8 KB epilogue tile)
// -> 4 blocks/CU residency; grid 768 = 3/CU = one uniform round. Per iter:
// barrier -> issue DMA -> drain-barrier -> 32 MFMA. Co-resident blocks hide
// the DMA latency. Q pre-scaled 0.125*log2e.
// ---------------------------------------------------------------------------
#define QSCALE 0.180336879f   // 0.125 * 1.44269504

__global__ __launch_bounds__(256, 3) void qkv_gemm_kernel(
    const unsigned short* __restrict__ xnb, const unsigned short* __restrict__ wt,
    const float* __restrict__ bias, unsigned short* __restrict__ qkvb) {
  __shared__ __align__(16) char smem[34816];
  short (*As)[64] = (short (*)[64])smem;             // 16384 B
  short (*Bs)[64] = (short (*)[64])(smem + 16384);   // 16384 B
  short (*T)[136] = (short (*)[136])smem;            // epilogue tile, 34816 B

  int tn = blockIdx.x;          // 0..11  (part = tn>>2)
  int tm = blockIdx.y;          // 0..63
  int tid = threadIdx.x;
  int wv = tid >> 6, lane = tid & 63;
  int quad = lane >> 4, l16 = lane & 15;
  int wm = wv >> 1, wn = wv & 1;
  int l7 = l16 & 7;

  int kr = lane >> 3;
  int kg = (lane & 7) ^ kr;

  floatx4 acc[4][4];
  for (int i = 0; i < 4; i++) for (int j = 0; j < 4; j++) acc[i][j] = fzero4();

  for (int it = 0; it < 8; it++) {
    __syncthreads();   // (a) previous tile's LDS reads done
    int k0 = it * 64;
    for (int i = 0; i < 4; i++) {
      int rb = i * 32 + wv * 8;
      async_cp16(&xnb[(size_t)(tm * 128 + rb + kr) * 512 + k0 + kg * 8], &As[rb][0]);
      async_cp16(&wt [(size_t)(tn * 128 + rb + kr) * 512 + k0 + kg * 8], &Bs[rb][0]);
    }
    __syncthreads();   // (b) vmcnt drain -> tile visible
    for (int kk = 0; kk < 2; kk++) {
      short8 a[4], b[4];
      for (int mt = 0; mt < 4; mt++)
        a[mt] = *(const short8*)&As[wm * 64 + mt * 16 + l16][((kk * 4 + quad) ^ l7) * 8];
      for (int nt = 0; nt < 4; nt++)
        b[nt] = *(const short8*)&Bs[wn * 64 + nt * 16 + l16][((kk * 4 + quad) ^ l7) * 8];
      for (int mt = 0; mt < 4; mt++)
        for (int nt = 0; nt < 4; nt++)
          acc[mt][nt] = __builtin_amdgcn_mfma_f32_16x16x32_bf16(a[mt], b[nt], acc[mt][nt], 0, 0, 0);
    }
  }
  __syncthreads();   // before smem reuse as T

  int part = tn >> 2;
  int b = tm >> 5;
  int tloc = (tm & 31) * 128;

  if (part < 2) {
    for (int nt = 0; nt < 4; nt++) {
      int coll = wn * 64 + nt * 16 + l16;
      float bv = bias[tn * 128 + coll];
      for (int mt = 0; mt < 4; mt++) {
        int rowb = wm * 64 + mt * 16 + quad * 4;
        for (int r = 0; r < 4; r++) {
          float v = acc[mt][nt][r] + bv;
          if (part == 0) v *= QSCALE;
          T[rowb + r][coll] = (short)f2bf(v);
        }
      }
    }
    __syncthreads();
    int h0 = (tn & 3) * 2;
    for (int it = 0; it < 8; it++) {
      int row = it * 16 + (tid >> 4);
      int l = tid & 15;
      uint4 vv = *(uint4*)&T[row][l * 8];
      int h = h0 + (l >> 3), d = (l & 7) * 8;
      size_t idx = (size_t)part * PS +
                   ((size_t)((b * 8 + h) * 4096 + tloc + row)) * 64 + d;
      *(uint4*)&qkvb[idx] = vv;
    }
  } else {
    for (int nt = 0; nt < 4; nt++) {
      int coll = wn * 64 + nt * 16 + l16;
      float bv = bias[tn * 128 + coll];
      for (int mt = 0; mt < 4; mt++) {
        int rowb = wm * 64 + mt * 16 + quad * 4;
        uint2 w;
        w.x = pack_bf2(acc[mt][nt][0] + bv, acc[mt][nt][1] + bv);
        w.y = pack_bf2(acc[mt][nt][2] + bv, acc[mt][nt][3] + bv);
        *(uint2*)&T[coll][rowb] = w;
      }
    }
    __syncthreads();
    for (int it = 0; it < 8; it++) {
      int vrow = it * 16 + (tid >> 4);
      int l = tid & 15;
      uint4 vv = *(uint4*)&T[vrow][l * 8];
      int gj = tn * 128 + vrow;
      int h = (gj >> 6) & 7, d = gj & 63;
      size_t idx = 2 * (size_t)PS +
                   ((size_t)((b * 8 + h) * 64 + d)) * 4096 + tloc + l * 8;
      *(uint4*)&qkvb[idx] = vv;
    }
  }
}

// ---------------------------------------------------------------------------
// Kernel 3: flash attention, split-K2, SINGLE-buffered K/V (32 KB loop LDS,
// 34.8 KB epilogue alias) -> 4 blocks/CU; grid 32x16x2 = 1024 = ALL blocks
// resident simultaneously (zero rounds, zero tail). Fixed-max exp2 softmax;
// register-resident P via K=16 MFMA; bf16 unnormalized partials + fp32 l.
// ---------------------------------------------------------------------------
#define SMEM_ATT 34816

__global__ __launch_bounds__(256, 4) void attn_kernel(
    const unsigned short* __restrict__ qkvb, unsigned short* __restrict__ valp,
    float* __restrict__ lsum) {
  __shared__ __align__(16) char smem[SMEM_ATT];
  short (*Ks)[64]   = (short (*)[64])smem;            // 16384 B
  short (*Vt)[128]  = (short (*)[128])(smem + 16384); // 16384 B
  float (*slab)[68] = (float (*)[68])smem;            // epilogue alias

  int bh = blockIdx.y;
  int qb = blockIdx.x * 128;
  int ksp = blockIdx.z;                      // 0,1
  int tid = threadIdx.x;
  int wv = tid >> 6, lane = tid & 63, quad = lane >> 4, l16 = lane & 15;
  int l7 = l16 & 7;
  const unsigned short* Qg = qkvb + (size_t)bh * NN * DD;
  const unsigned short* Kg = qkvb + (size_t)PS + (size_t)bh * NN * DD +
                             (size_t)ksp * 2048 * DD;
  const unsigned short* Vg = qkvb + 2 * (size_t)PS + (size_t)bh * DD * NN +
                             (size_t)ksp * 2048;

  int kr = lane >> 3;
  int kg = (lane & 7) ^ kr;
  int vr = lane >> 4;
  int vgr = (lane & 15) ^ ((wv * 4 + vr) & 15);

  // ---- Stage Q tile (128x64) via DMA, pull B-fragments to regs.
  for (int i = 0; i < 4; i++) {
    int rb = i * 32 + wv * 8;
    async_cp16(&Qg[(size_t)(qb + rb + kr) * 64 + kg * 8], &Ks[rb][0]);
  }
  __syncthreads();
  short8 qf[2][2];
  for (int g = 0; g < 2; g++)
    for (int kk = 0; kk < 2; kk++)
      qf[g][kk] = *(const short8*)&Ks[wv * 32 + g * 16 + l16][((kk * 4 + quad) ^ l7) * 8];

  floatx4 o[2][4];
  for (int g = 0; g < 2; g++) for (int dt = 0; dt < 4; dt++) o[g][dt] = fzero4();
  float ls[2] = {0.0f, 0.0f};

  for (int kt = 0; kt < 16; kt++) {
    __syncthreads();   // (a) prev tile reads done (kt=0: qf reads done)
    int kn = kt * 128;
    for (int i = 0; i < 4; i++) {
      int rb = i * 32 + wv * 8;
      async_cp16(&Kg[(size_t)(kn + rb + kr) * 64 + kg * 8], &Ks[rb][0]);
    }
    for (int i = 0; i < 4; i++) {
      int rb = i * 16 + wv * 4;
      async_cp16(&Vg[(size_t)(rb + vr) * NN + kn + vgr * 8], &Vt[rb][0]);
    }
    __syncthreads();   // (b) vmcnt drain -> K(kt), V(kt) visible

    // ---- S^T = K·Q^T
    floatx4 s[2][8];
    for (int nt = 0; nt < 8; nt++) {
      short8 kf0 = *(const short8*)&Ks[nt * 16 + l16][((quad) ^ l7) * 8];
      short8 kf1 = *(const short8*)&Ks[nt * 16 + l16][((4 + quad) ^ l7) * 8];
      floatx4 s0 = fzero4(), s1 = fzero4();
      s0 = __builtin_amdgcn_mfma_f32_16x16x32_bf16(kf0, qf[0][0], s0, 0, 0, 0);
      s0 = __builtin_amdgcn_mfma_f32_16x16x32_bf16(kf1, qf[0][1], s0, 0, 0, 0);
      s1 = __builtin_amdgcn_mfma_f32_16x16x32_bf16(kf0, qf[1][0], s1, 0, 0, 0);
      s1 = __builtin_amdgcn_mfma_f32_16x16x32_bf16(kf1, qf[1][1], s1, 0, 0, 0);
      s[0][nt] = s0;
      s[1][nt] = s1;
    }

    // ---- p = exp2(s); P stays in registers as the K=16 MFMA B-operand.
    for (int nt = 0; nt < 8; nt++) {
      float p00 = __builtin_amdgcn_exp2f(s[0][nt][0]);
      float p01 = __builtin_amdgcn_exp2f(s[0][nt][1]);
      float p02 = __builtin_amdgcn_exp2f(s[0][nt][2]);
      float p03 = __builtin_amdgcn_exp2f(s[0][nt][3]);
      float p10 = __builtin_amdgcn_exp2f(s[1][nt][0]);
      float p11 = __builtin_amdgcn_exp2f(s[1][nt][1]);
      float p12 = __builtin_amdgcn_exp2f(s[1][nt][2]);
      float p13 = __builtin_amdgcn_exp2f(s[1][nt][3]);
      ls[0] += (p00 + p01) + (p02 + p03);
      ls[1] += (p10 + p11) + (p12 + p13);
      short4v pa0 = pack_bf4(p00, p01, p02, p03);
      short4v pa1 = pack_bf4(p10, p11, p12, p13);
      for (int dt = 0; dt < 4; dt++) {
        short4v vb = *(const short4v*)&Vt[dt * 16 + l16]
            [(((nt * 2 + (quad >> 1)) ^ l16) * 8) + (quad & 1) * 4];
        o[0][dt] = MFMA16(vb, pa0, o[0][dt]);
        o[1][dt] = MFMA16(vb, pa1, o[1][dt]);
      }
    }
  }

  // ---- l reduction across quads
  for (int g = 0; g < 2; g++) {
    ls[g] += __shfl_xor(ls[g], 16, 64);
    ls[g] += __shfl_xor(ls[g], 32, 64);
  }
  float* lrow = lsum + (size_t)(ksp * 16 + bh) * 4096 + qb;
  if (lane < 16) {
    lrow[wv * 32 + l16] = ls[0];
    lrow[wv * 32 + 16 + l16] = ls[1];
  }

  // ---- Epilogue: unnormalized O^T -> slab [q][d] fp32 -> bf16 global write
  __syncthreads();
  for (int g = 0; g < 2; g++) {
    int q = wv * 32 + g * 16 + l16;
    for (int dt = 0; dt < 4; dt++)
      for (int r = 0; r < 4; r++)
        slab[q][dt * 16 + quad * 4 + r] = o[g][dt][r];
  }
  __syncthreads();
  int b = bh >> 3, h = bh & 7;
  unsigned short* myval = valp + (size_t)ksp * MR * CC;
  for (int it = 0; it < 4; it++) {
    int row = it * 32 + (tid >> 3);
    int col8 = (tid & 7) * 8;
    float4 a = *(float4*)&slab[row][col8];
    float4 c = *(float4*)&slab[row][col8 + 4];
    uint4 u;
    u.x = pack_bf2(a.x, a.y);  u.y = pack_bf2(a.z, a.w);
    u.z = pack_bf2(c.x, c.y);  u.w = pack_bf2(c.z, c.w);
    *(uint4*)&myval[((size_t)(b * 4096 + qb + row)) * 512 + h * 64 + col8] = u;
  }
}

// ---------------------------------------------------------------------------
// Kernel 4: combine 2 splits + post-LayerNorm + residual (from bf16 xnb).
// out = xnb + LN((O0+O1)/(l0+l1)); one wave per row, 8 cols/lane.
// ---------------------------------------------------------------------------
__global__ __launch_bounds__(256) void post_ln_kernel(
    const unsigned short* __restrict__ valp, const float* __restrict__ lsum,
    const unsigned short* __restrict__ xnb,
    const float* __restrict__ g, const float* __restrict__ be,
    float* __restrict__ out) {
  int wv = threadIdx.x >> 6, lane = threadIdx.x & 63;
  int row = blockIdx.x * 4 + wv;         // b*4096 + q
  int b = row >> 12, q = row & 4095;
  int h = lane >> 3;                     // 8 lanes per head
  float acc[8];
  for (int j = 0; j < 8; j++) acc[j] = 0.0f;
  float lt = 0.0f;
  for (int sp = 0; sp < 2; sp++) {
    uint4 u = *(const uint4*)&valp[((size_t)sp * MR + row) * CC + lane * 8];
    acc[0] += __uint_as_float(u.x << 16);
    acc[1] += __uint_as_float(u.x & 0xffff0000u);
    acc[2] += __uint_as_float(u.y << 16);
    acc[3] += __uint_as_float(u.y & 0xffff0000u);
    acc[4] += __uint_as_float(u.z << 16);
    acc[5] += __uint_as_float(u.z & 0xffff0000u);
    acc[6] += __uint_as_float(u.w << 16);
    acc[7] += __uint_as_float(u.w & 0xffff0000u);
    lt += lsum[(size_t)(sp * 16 + b * 8 + h) * 4096 + q];
  }
  float inv = 1.0f / lt;
  float s = 0.0f, sq = 0.0f;
  for (int j = 0; j < 8; j++) {
    acc[j] *= inv;
    s += acc[j];
    sq += acc[j] * acc[j];
  }
  for (int off = 1; off < 64; off <<= 1) {
    s  += __shfl_xor(s,  off, 64);
    sq += __shfl_xor(sq, off, 64);
  }
  float mean = s * (1.0f / CC);
  float var  = sq * (1.0f / CC) - mean * mean;
  float rstd = rsqrtf(var + 1e-5f);
  float4 g0 = ((const float4*)g)[lane * 2];
  float4 g1 = ((const float4*)g)[lane * 2 + 1];
  float4 b0 = ((const float4*)be)[lane * 2];
  float4 b1 = ((const float4*)be)[lane * 2 + 1];
  size_t base = (size_t)row * CC + lane * 8;
  uint4 xr = *(const uint4*)&xnb[base];
  float r[8];
  r[0] = __uint_as_float(xr.x << 16);  r[1] = __uint_as_float(xr.x & 0xffff0000u);
  r[2] = __uint_as_float(xr.y << 16);  r[3] = __uint_as_float(xr.y & 0xffff0000u);
  r[4] = __uint_as_float(xr.z << 16);  r[5] = __uint_as_float(xr.z & 0xffff0000u);
  r[6] = __uint_as_float(xr.w << 16);  r[7] = __uint_as_float(xr.w & 0xffff0000u);
  float4 o0, o1;
  o0.x = (acc[0] - mean) * rstd * g0.x + b0.x + r[0];
  o0.y = (acc[1] - mean) * rstd * g0.y + b0.y + r[1];
  o0.z = (acc[2] - mean) * rstd * g0.z + b0.z + r[2];
  o0.w = (acc[3] - mean) * rstd * g0.w + b0.w + r[3];
  o1.x = (acc[4] - mean) * rstd * g1.x + b1.x + r[4];
  o1.y = (acc[5] - mean) * rstd * g1.y + b1.y + r[5];
  o1.z = (acc[6] - mean) * rstd * g1.z + b1.z + r[6];
  o1.w = (acc[7] - mean) * rstd * g1.w + b1.w + r[7];
  *(float4*)&out[base] = o0;
  *(float4*)&out[base + 4] = o1;
}

// ---------------------------------------------------------------------------
extern "C" void kernel_launch(void* const* d_in, const int* in_sizes, int n_in,
                              void* d_out, int out_size, void* d_ws, size_t ws_size,
                              hipStream_t stream) {
  const float* x       = (const float*)d_in[0];
  const float* w_qkv   = (const float*)d_in[1];
  const float* b_qkv   = (const float*)d_in[2];
  const float* g_pre   = (const float*)d_in[3];
  const float* be_pre  = (const float*)d_in[4];
  const float* g_post  = (const float*)d_in[5];
  const float* be_post = (const float*)d_in[6];
  float* out = (float*)d_out;

  // ws: val partials bf16 2x8MB | lsum 512KB | xnb 8MB | qkvb 24MB | wt 1.5MB
  unsigned short* val  = (unsigned short*)d_ws;
  float* lsum = (float*)(val + 2 * (size_t)MR * CC);
  unsigned short* xnb  = (unsigned short*)(lsum + 2 * 16 * 4096);
  unsigned short* qkvb = xnb + 4194304;
  unsigned short* wt   = qkvb + 3 * (size_t)PS;

  convert_w_kernel<<<dim3(24, 8), 256, 0, stream>>>(w_qkv, wt);
  pre_ln_kernel<<<2048, 256, 0, stream>>>(x, g_pre, be_pre, xnb);
  qkv_gemm_kernel<<<dim3(12, 64), 256, 0, stream>>>(xnb, wt, b_qkv, qkvb);
  attn_kernel<<<dim3(32, 16, 2), 256, 0, stream>>>(qkvb, val, lsum);
  post_ln_kernel<<<2048, 256, 0, stream>>>(val, lsum, xnb, g_post, be_post, out);
}

// Round 10
// 196.552 us; speedup vs baseline: 1.3004x; 1.3004x over previous
//
#include <hip/hip_runtime.h>

// Problem constants
#define BB   2
#define NN   4096
#define CC   512
#define HH   8
#define DD   64
#define MR   8192          // B*N rows
#define NC3  1536          // 3*C
#define PS   4194304       // per-part stride in qkv buffer = B*H*N*D
#define SPLK 1408          // keys per split (splits 0,1); split 2 gets 1280

typedef __attribute__((ext_vector_type(8))) short short8;
typedef __attribute__((ext_vector_type(4))) short short4v;
typedef __attribute__((ext_vector_type(4))) float floatx4;

// K=16 bf16 MFMA: B-layout B[k=quad*4+j][n=l16] == 16x16 C-layout -> P stays
// in registers between QK^T and PV.
#if __has_builtin(__builtin_amdgcn_mfma_f32_16x16x16_bf16_1k)
#define MFMA16(a, b, c) __builtin_amdgcn_mfma_f32_16x16x16_bf16_1k(a, b, c, 0, 0, 0)
#elif __has_builtin(__builtin_amdgcn_mfma_f32_16x16x16_bf16)
#define MFMA16(a, b, c) __builtin_amdgcn_mfma_f32_16x16x16_bf16(a, b, c, 0, 0, 0)
#else
__device__ inline floatx4 mfma16_asm(short4v a, short4v b, floatx4 c) {
  asm volatile("v_mfma_f32_16x16x16_bf16 %0, %1, %2, %0" : "+v"(c) : "v"(a), "v"(b));
  return c;
}
#define MFMA16(a, b, c) mfma16_asm(a, b, c)
#endif

__device__ inline unsigned short f2bf(float f) {
  unsigned int u = __float_as_uint(f);
  u = (u + 0x7fffu + ((u >> 16) & 1u)) >> 16;
  return (unsigned short)u;
}

// pack two fp32 -> bf16x2 (round-half-up) in 3 VALU ops via v_perm_b32:
// result = hi16(b+0x8000) : hi16(a+0x8000)
__device__ inline unsigned int pack_bf2(float a, float b) {
  return __builtin_amdgcn_perm(__float_as_uint(b) + 0x8000u,
                               __float_as_uint(a) + 0x8000u, 0x07060302u);
}

__device__ inline short4v pack_bf4(float a, float b, float c, float d) {
  union { unsigned int u[2]; short4v v; } t;
  t.u[0] = pack_bf2(a, b);
  t.u[1] = pack_bf2(c, d);
  return t.v;
}

__device__ inline floatx4 fzero4() { floatx4 z = {0.f, 0.f, 0.f, 0.f}; return z; }

__device__ inline void async_cp16(const void* g, void* l) {
  __builtin_amdgcn_global_load_lds(
      (const __attribute__((address_space(1))) unsigned int*)g,
      (__attribute__((address_space(3))) unsigned int*)l, 16, 0, 0);
}

// ---------------------------------------------------------------------------
// Kernel 0: convert + transpose w_qkv [512,1536] fp32 -> wt [1536,512] bf16.
// ---------------------------------------------------------------------------
__global__ __launch_bounds__(256) void convert_w_kernel(
    const float* __restrict__ w, unsigned short* __restrict__ wt) {
  __shared__ short T[64][68];
  int bn = blockIdx.x;                   // 0..23
  int bk = blockIdx.y;                   // 0..7
  int tid = threadIdx.x;
  for (int p = 0; p < 4; p++) {
    int k = p * 16 + (tid >> 4);
    int n4 = (tid & 15) * 4;
    float4 v = *(const float4*)&w[(size_t)(bk * 64 + k) * NC3 + bn * 64 + n4];
    T[n4 + 0][k] = (short)f2bf(v.x);
    T[n4 + 1][k] = (short)f2bf(v.y);
    T[n4 + 2][k] = (short)f2bf(v.z);
    T[n4 + 3][k] = (short)f2bf(v.w);
  }
  __syncthreads();
  for (int p = 0; p < 2; p++) {
    int n = p * 32 + (tid >> 3);
    int k8 = (tid & 7) * 8;
    uint4 v = *(uint4*)&T[n][k8];
    *(uint4*)&wt[(size_t)(bn * 64 + n) * 512 + bk * 64 + k8] = v;
  }
}

// ---------------------------------------------------------------------------
// Kernel 1: pre-LayerNorm, one wave per row, bf16 output only.
// ---------------------------------------------------------------------------
__global__ __launch_bounds__(256) void pre_ln_kernel(
    const float* __restrict__ x, const float* __restrict__ g,
    const float* __restrict__ be, unsigned short* __restrict__ xnb) {
  int wv = threadIdx.x >> 6, lane = threadIdx.x & 63;
  int row = blockIdx.x * 4 + wv;
  const float4* xr = (const float4*)(x + (size_t)row * CC);
  float4 v0 = xr[lane];
  float4 v1 = xr[64 + lane];
  float s  = (v0.x + v0.y) + (v0.z + v0.w) + (v1.x + v1.y) + (v1.z + v1.w);
  float sq = (v0.x * v0.x + v0.y * v0.y) + (v0.z * v0.z + v0.w * v0.w) +
             (v1.x * v1.x + v1.y * v1.y) + (v1.z * v1.z + v1.w * v1.w);
  for (int off = 1; off < 64; off <<= 1) {
    s  += __shfl_xor(s,  off, 64);
    sq += __shfl_xor(sq, off, 64);
  }
  float mean = s * (1.0f / CC);
  float var  = sq * (1.0f / CC) - mean * mean;
  float rstd = rsqrtf(var + 1e-5f);
  const float4* gg = (const float4*)g;
  const float4* bb = (const float4*)be;
  float4 g0 = gg[lane], g1 = gg[64 + lane];
  float4 b0 = bb[lane], b1 = bb[64 + lane];
  float4 o0, o1;
  o0.x = (v0.x - mean) * rstd * g0.x + b0.x;
  o0.y = (v0.y - mean) * rstd * g0.y + b0.y;
  o0.z = (v0.z - mean) * rstd * g0.z + b0.z;
  o0.w = (v0.w - mean) * rstd * g0.w + b0.w;
  o1.x = (v1.x - mean) * rstd * g1.x + b1.x;
  o1.y = (v1.y - mean) * rstd * g1.y + b1.y;
  o1.z = (v1.z - mean) * rstd * g1.z + b1.z;
  o1.w = (v1.w - mean) * rstd * g1.w + b1.w;
  size_t base = (size_t)row * CC;
  uint2 u0, u1;
  u0.x = pack_bf2(o0.x, o0.y); u0.y = pack_bf2(o0.z, o0.w);
  u1.x = pack_bf2(o1.x, o1.y); u1.y = pack_bf2(o1.z, o1.w);
  *(uint2*)&xnb[base + 4 * lane] = u0;
  *(uint2*)&xnb[base + 256 + 4 * lane] = u1;
}

// ---------------------------------------------------------------------------
// Kernel 2: QKV GEMM (R8 ping-pong DMA pipeline). XOR-swizzled LDS,
// coalesced LDS-routed epilogue. Q pre-scaled 0.125*log2e.
// ---------------------------------------------------------------------------
#define QSCALE 0.180336879f   // 0.125 * 1.44269504

__global__ __launch_bounds__(256) void qkv_gemm_kernel(
    const unsigned short* __restrict__ xnb, const unsigned short* __restrict__ wt,
    const float* __restrict__ bias, unsigned short* __restrict__ qkvb) {
  __shared__ __align__(16) char smem[65536];
  short (*Asb[2])[64];
  short (*Bsb[2])[64];
  Asb[0] = (short (*)[64])smem;
  Bsb[0] = (short (*)[64])(smem + 16384);
  Asb[1] = (short (*)[64])(smem + 32768);
  Bsb[1] = (short (*)[64])(smem + 49152);
  short (*T)[136] = (short (*)[136])smem;

  int tn = blockIdx.x;          // 0..11  (part = tn>>2)
  int tm = blockIdx.y;          // 0..63
  int tid = threadIdx.x;
  int wv = tid >> 6, lane = tid & 63;
  int quad = lane >> 4, l16 = lane & 15;
  int wm = wv >> 1, wn = wv & 1;
  int l7 = l16 & 7;

  int kr = lane >> 3;
  int kg = (lane & 7) ^ kr;

  floatx4 acc[4][4];
  for (int i = 0; i < 4; i++) for (int j = 0; j < 4; j++) acc[i][j] = fzero4();

  for (int i = 0; i < 4; i++) {
    int rb = i * 32 + wv * 8;
    async_cp16(&xnb[(size_t)(tm * 128 + rb + kr) * 512 + kg * 8], &Asb[0][rb][0]);
    async_cp16(&wt [(size_t)(tn * 128 + rb + kr) * 512 + kg * 8], &Bsb[0][rb][0]);
  }

  for (int it = 0; it < 8; it++) {
    __syncthreads();
    short (*As)[64] = Asb[it & 1];
    short (*Bs)[64] = Bsb[it & 1];
    if (it < 7) {
      int kn = (it + 1) * 64;
      short (*An)[64] = Asb[(it + 1) & 1];
      short (*Bn)[64] = Bsb[(it + 1) & 1];
      for (int i = 0; i < 4; i++) {
        int rb = i * 32 + wv * 8;
        async_cp16(&xnb[(size_t)(tm * 128 + rb + kr) * 512 + kn + kg * 8], &An[rb][0]);
        async_cp16(&wt [(size_t)(tn * 128 + rb + kr) * 512 + kn + kg * 8], &Bn[rb][0]);
      }
    }
    for (int kk = 0; kk < 2; kk++) {
      short8 a[4], b[4];
      for (int mt = 0; mt < 4; mt++)
        a[mt] = *(const short8*)&As[wm * 64 + mt * 16 + l16][((kk * 4 + quad) ^ l7) * 8];
      for (int nt = 0; nt < 4; nt++)
        b[nt] = *(const short8*)&Bs[wn * 64 + nt * 16 + l16][((kk * 4 + quad) ^ l7) * 8];
      for (int mt = 0; mt < 4; mt++)
        for (int nt = 0; nt < 4; nt++)
          acc[mt][nt] = __builtin_amdgcn_mfma_f32_16x16x32_bf16(a[mt], b[nt], acc[mt][nt], 0, 0, 0);
    }
  }
  __syncthreads();

  int part = tn >> 2;
  int b = tm >> 5;
  int tloc = (tm & 31) * 128;

  if (part < 2) {
    for (int nt = 0; nt < 4; nt++) {
      int coll = wn * 64 + nt * 16 + l16;
      float bv = bias[tn * 128 + coll];
      for (int mt = 0; mt < 4; mt++) {
        int rowb = wm * 64 + mt * 16 + quad * 4;
        for (int r = 0; r < 4; r++) {
          float v = acc[mt][nt][r] + bv;
          if (part == 0) v *= QSCALE;
          T[rowb + r][coll] = (short)f2bf(v);
        }
      }
    }
    __syncthreads();
    int h0 = (tn & 3) * 2;
    for (int it = 0; it < 8; it++) {
      int row = it * 16 + (tid >> 4);
      int l = tid & 15;
      uint4 vv = *(uint4*)&T[row][l * 8];
      int h = h0 + (l >> 3), d = (l & 7) * 8;
      size_t idx = (size_t)part * PS +
                   ((size_t)((b * 8 + h) * 4096 + tloc + row)) * 64 + d;
      *(uint4*)&qkvb[idx] = vv;
    }
  } else {
    for (int nt = 0; nt < 4; nt++) {
      int coll = wn * 64 + nt * 16 + l16;
      float bv = bias[tn * 128 + coll];
      for (int mt = 0; mt < 4; mt++) {
        int rowb = wm * 64 + mt * 16 + quad * 4;
        uint2 w;
        w.x = pack_bf2(acc[mt][nt][0] + bv, acc[mt][nt][1] + bv);
        w.y = pack_bf2(acc[mt][nt][2] + bv, acc[mt][nt][3] + bv);
        *(uint2*)&T[coll][rowb] = w;
      }
    }
    __syncthreads();
    for (int it = 0; it < 8; it++) {
      int vrow = it * 16 + (tid >> 4);
      int l = tid & 15;
      uint4 vv = *(uint4*)&T[vrow][l * 8];
      int gj = tn * 128 + vrow;
      int h = (gj >> 6) & 7, d = gj & 63;
      size_t idx = 2 * (size_t)PS +
                   ((size_t)((b * 8 + h) * 64 + d)) * 4096 + tloc + l * 8;
      *(uint4*)&qkvb[idx] = vv;
    }
  }
}

// ---------------------------------------------------------------------------
// Kernel 3: flash attention, split-K3 (R8 structure: split-barrier pipeline,
// V double-buffered, 48 KB LDS, 3 blocks/CU). Fixed-max exp2 softmax;
// register-resident P; l computed by ones-row MFMA (no VALU adds, no final
// shuffle reduce); bf16 unnormalized partials + fp32 l sums.
// ---------------------------------------------------------------------------
#define SMEM_ATT (16384 + 32768)

__global__ __launch_bounds__(256, 3) void attn_kernel(
    const unsigned short* __restrict__ qkvb, unsigned short* __restrict__ valp,
    float* __restrict__ lsum) {
  __shared__ __align__(16) char smem[SMEM_ATT];
  short (*Ks)[64]   = (short (*)[64])smem;
  short (*Vt0)[128] = (short (*)[128])(smem + 16384);
  short (*Vt1)[128] = (short (*)[128])(smem + 32768);
  float (*slab)[68] = (float (*)[68])smem;   // epilogue alias

  int bh = blockIdx.y;
  int qb = blockIdx.x * 128;
  int ksp = blockIdx.z;                      // 0,1,2
  int kts = (ksp < 2) ? 11 : 10;             // 11*128, 11*128, 10*128 keys
  int tid = threadIdx.x;
  int wv = tid >> 6, lane = tid & 63, quad = lane >> 4, l16 = lane & 15;
  int l7 = l16 & 7;
  const unsigned short* Qg = qkvb + (size_t)bh * NN * DD;
  const unsigned short* Kg = qkvb + (size_t)PS + (size_t)bh * NN * DD +
                             (size_t)ksp * SPLK * DD;
  const unsigned short* Vg = qkvb + 2 * (size_t)PS + (size_t)bh * DD * NN +
                             (size_t)ksp * SPLK;

  int kr = lane >> 3;
  int kg = (lane & 7) ^ kr;
  int vr = lane >> 4;
  int vgr = (lane & 15) ^ ((wv * 4 + vr) & 15);

  // ones A-fragment: row m=0 (lanes l16==0) = 1.0 bf16, else 0.
  union { unsigned int u[2]; short4v v; } von;
  von.u[0] = (l16 == 0) ? 0x3F803F80u : 0u;
  von.u[1] = von.u[0];
  short4v vones = von.v;

  // ---- Stage Q tile (128x64) via DMA, pull B-fragments to regs.
  for (int i = 0; i < 4; i++) {
    int rb = i * 32 + wv * 8;
    async_cp16(&Qg[(size_t)(qb + rb + kr) * 64 + kg * 8], &Ks[rb][0]);
  }
  __syncthreads();
  short8 qf[2][2];
  for (int g = 0; g < 2; g++)
    for (int kk = 0; kk < 2; kk++)
      qf[g][kk] = *(const short8*)&Ks[wv * 32 + g * 16 + l16][((kk * 4 + quad) ^ l7) * 8];
  __syncthreads();

  // ---- Prologue DMA: K(0), V(0)
  for (int i = 0; i < 4; i++) {
    int rb = i * 32 + wv * 8;
    async_cp16(&Kg[(size_t)(rb + kr) * 64 + kg * 8], &Ks[rb][0]);
  }
  for (int i = 0; i < 4; i++) {
    int rb = i * 16 + wv * 4;
    async_cp16(&Vg[(size_t)(rb + vr) * NN + vgr * 8], &Vt0[rb][0]);
  }

  floatx4 o[2][4];
  for (int g = 0; g < 2; g++) for (int dt = 0; dt < 4; dt++) o[g][dt] = fzero4();
  floatx4 ol[2];
  ol[0] = fzero4();  ol[1] = fzero4();

  for (int kt = 0; kt < kts; kt++) {
    __syncthreads();   // vmcnt drained -> Ks=K(kt), Vt[kt&1]=V(kt)
    short (*Vc)[128] = (kt & 1) ? Vt1 : Vt0;
    short (*Vn)[128] = (kt & 1) ? Vt0 : Vt1;
    if (kt + 1 < kts) {
      int kn = (kt + 1) * 128;
      for (int i = 0; i < 4; i++) {
        int rb = i * 16 + wv * 4;
        async_cp16(&Vg[(size_t)(rb + vr) * NN + kn + vgr * 8], &Vn[rb][0]);
      }
    }

    // ---- S^T = K·Q^T
    floatx4 s[2][8];
    for (int nt = 0; nt < 8; nt++) {
      short8 kf0 = *(const short8*)&Ks[nt * 16 + l16][((quad) ^ l7) * 8];
      short8 kf1 = *(const short8*)&Ks[nt * 16 + l16][((4 + quad) ^ l7) * 8];
      floatx4 s0 = fzero4(), s1 = fzero4();
      s0 = __builtin_amdgcn_mfma_f32_16x16x32_bf16(kf0, qf[0][0], s0, 0, 0, 0);
      s0 = __builtin_amdgcn_mfma_f32_16x16x32_bf16(kf1, qf[0][1], s0, 0, 0, 0);
      s1 = __builtin_amdgcn_mfma_f32_16x16x32_bf16(kf0, qf[1][0], s1, 0, 0, 0);
      s1 = __builtin_amdgcn_mfma_f32_16x16x32_bf16(kf1, qf[1][1], s1, 0, 0, 0);
      s[0][nt] = s0;
      s[1][nt] = s1;
    }
    __syncthreads();   // all waves done reading Ks
    if (kt + 1 < kts) {
      int kn = (kt + 1) * 128;
      for (int i = 0; i < 4; i++) {
        int rb = i * 32 + wv * 8;
        async_cp16(&Kg[(size_t)(kn + rb + kr) * 64 + kg * 8], &Ks[rb][0]);
      }
    }

    // ---- p = exp2(s); P stays in registers; l accumulated via ones-MFMA.
    for (int nt = 0; nt < 8; nt++) {
      float p00 = __builtin_amdgcn_exp2f(s[0][nt][0]);
      float p01 = __builtin_amdgcn_exp2f(s[0][nt][1]);
      float p02 = __builtin_amdgcn_exp2f(s[0][nt][2]);
      float p03 = __builtin_amdgcn_exp2f(s[0][nt][3]);
      float p10 = __builtin_amdgcn_exp2f(s[1][nt][0]);
      float p11 = __builtin_amdgcn_exp2f(s[1][nt][1]);
      float p12 = __builtin_amdgcn_exp2f(s[1][nt][2]);
      float p13 = __builtin_amdgcn_exp2f(s[1][nt][3]);
      short4v pa0 = pack_bf4(p00, p01, p02, p03);
      short4v pa1 = pack_bf4(p10, p11, p12, p13);
      ol[0] = MFMA16(vones, pa0, ol[0]);
      ol[1] = MFMA16(vones, pa1, ol[1]);
      for (int dt = 0; dt < 4; dt++) {
        short4v vb = *(const short4v*)&Vc[dt * 16 + l16]
            [(((nt * 2 + (quad >> 1)) ^ l16) * 8) + (quad & 1) * 4];
        o[0][dt] = MFMA16(vb, pa0, o[0][dt]);
        o[1][dt] = MFMA16(vb, pa1, o[1][dt]);
      }
    }
  }

  // ---- l lives in C-row 0 (quad==0, reg 0), col = q = l16.
  float* lrow = lsum + (size_t)(ksp * 16 + bh) * 4096 + qb;
  if (quad == 0) {
    lrow[wv * 32 + l16] = ol[0][0];
    lrow[wv * 32 + 16 + l16] = ol[1][0];
  }

  // ---- Epilogue: unnormalized O^T -> slab [q][d] fp32 -> bf16 global write
  __syncthreads();
  for (int g = 0; g < 2; g++) {
    int q = wv * 32 + g * 16 + l16;
    for (int dt = 0; dt < 4; dt++)
      for (int r = 0; r < 4; r++)
        slab[q][dt * 16 + quad * 4 + r] = o[g][dt][r];
  }
  __syncthreads();
  int b = bh >> 3, h = bh & 7;
  unsigned short* myval = valp + (size_t)ksp * MR * CC;
  for (int it = 0; it < 4; it++) {
    int row = it * 32 + (tid >> 3);
    int col8 = (tid & 7) * 8;
    float4 a = *(float4*)&slab[row][col8];
    float4 c = *(float4*)&slab[row][col8 + 4];
    uint4 u;
    u.x = pack_bf2(a.x, a.y);  u.y = pack_bf2(a.z, a.w);
    u.z = pack_bf2(c.x, c.y);  u.w = pack_bf2(c.z, c.w);
    *(uint4*)&myval[((size_t)(b * 4096 + qb + row)) * 512 + h * 64 + col8] = u;
  }
}

// ---------------------------------------------------------------------------
// Kernel 4: combine 3 splits + post-LayerNorm + residual (from bf16 xnb).
// out = xnb + LN((O0+O1+O2)/(l0+l1+l2)); one wave per row, 8 cols/lane.
// ---------------------------------------------------------------------------
__global__ __launch_bounds__(256) void post_ln_kernel(
    const unsigned short* __restrict__ valp, const float* __restrict__ lsum,
    const unsigned short* __restrict__ xnb,
    const float* __restrict__ g, const float* __restrict__ be,
    float* __restrict__ out) {
  int wv = threadIdx.x >> 6, lane = threadIdx.x & 63;
  int row = blockIdx.x * 4 + wv;         // b*4096 + q
  int b = row >> 12, q = row & 4095;
  int h = lane >> 3;                     // 8 lanes per head
  float acc[8];
  for (int j = 0; j < 8; j++) acc[j] = 0.0f;
  float lt = 0.0f;
  for (int sp = 0; sp < 3; sp++) {
    uint4 u = *(const uint4*)&valp[((size_t)sp * MR + row) * CC + lane * 8];
    acc[0] += __uint_as_float(u.x << 16);
    acc[1] += __uint_as_float(u.x & 0xffff0000u);
    acc[2] += __uint_as_float(u.y << 16);
    acc[3] += __uint_as_float(u.y & 0xffff0000u);
    acc[4] += __uint_as_float(u.z << 16);
    acc[5] += __uint_as_float(u.z & 0xffff0000u);
    acc[6] += __uint_as_float(u.w << 16);
    acc[7] += __uint_as_float(u.w & 0xffff0000u);
    lt += lsum[(size_t)(sp * 16 + b * 8 + h) * 4096 + q];
  }
  float inv = 1.0f / lt;
  float s = 0.0f, sq = 0.0f;
  for (int j = 0; j < 8; j++) {
    acc[j] *= inv;
    s += acc[j];
    sq += acc[j] * acc[j];
  }
  for (int off = 1; off < 64; off <<= 1) {
    s  += __shfl_xor(s,  off, 64);
    sq += __shfl_xor(sq, off, 64);
  }
  float mean = s * (1.0f / CC);
  float var  = sq * (1.0f / CC) - mean * mean;
  float rstd = rsqrtf(var + 1e-5f);
  float4 g0 = ((const float4*)g)[lane * 2];
  float4 g1 = ((const float4*)g)[lane * 2 + 1];
  float4 b0 = ((const float4*)be)[lane * 2];
  float4 b1 = ((const float4*)be)[lane * 2 + 1];
  size_t base = (size_t)row * CC + lane * 8;
  uint4 xr = *(const uint4*)&xnb[base];
  float r[8];
  r[0] = __uint_as_float(xr.x << 16);  r[1] = __uint_as_float(xr.x & 0xffff0000u);
  r[2] = __uint_as_float(xr.y << 16);  r[3] = __uint_as_float(xr.y & 0xffff0000u);
  r[4] = __uint_as_float(xr.z << 16);  r[5] = __uint_as_float(xr.z & 0xffff0000u);
  r[6] = __uint_as_float(xr.w << 16);  r[7] = __uint_as_float(xr.w & 0xffff0000u);
  float4 o0, o1;
  o0.x = (acc[0] - mean) * rstd * g0.x + b0.x + r[0];
  o0.y = (acc[1] - mean) * rstd * g0.y + b0.y + r[1];
  o0.z = (acc[2] - mean) * rstd * g0.z + b0.z + r[2];
  o0.w = (acc[3] - mean) * rstd * g0.w + b0.w + r[3];
  o1.x = (acc[4] - mean) * rstd * g1.x + b1.x + r[4];
  o1.y = (acc[5] - mean) * rstd * g1.y + b1.y + r[5];
  o1.z = (acc[6] - mean) * rstd * g1.z + b1.z + r[6];
  o1.w = (acc[7] - mean) * rstd * g1.w + b1.w + r[7];
  *(float4*)&out[base] = o0;
  *(float4*)&out[base + 4] = o1;
}

// ---------------------------------------------------------------------------
extern "C" void kernel_launch(void* const* d_in, const int* in_sizes, int n_in,
                              void* d_out, int out_size, void* d_ws, size_t ws_size,
                              hipStream_t stream) {
  const float* x       = (const float*)d_in[0];
  const float* w_qkv   = (const float*)d_in[1];
  const float* b_qkv   = (const float*)d_in[2];
  const float* g_pre   = (const float*)d_in[3];
  const float* be_pre  = (const float*)d_in[4];
  const float* g_post  = (const float*)d_in[5];
  const float* be_post = (const float*)d_in[6];
  float* out = (float*)d_out;

  // ws: val partials bf16 3x8MB | lsum 768KB | xnb 8MB | qkvb 24MB | wt 1.5MB
  unsigned short* val  = (unsigned short*)d_ws;
  float* lsum = (float*)(val + 3 * (size_t)MR * CC);
  unsigned short* xnb  = (unsigned short*)(lsum + 3 * 16 * 4096);
  unsigned short* qkvb = xnb + 4194304;
  unsigned short* wt   = qkvb + 3 * (size_t)PS;

  convert_w_kernel<<<dim3(24, 8), 256, 0, stream>>>(w_qkv, wt);
  pre_ln_kernel<<<2048, 256, 0, stream>>>(x, g_pre, be_pre, xnb);
  qkv_gemm_kernel<<<dim3(12, 64), 256, 0, stream>>>(xnb, wt, b_qkv, qkvb);
  attn_kernel<<<dim3(32, 16, 3), 256, 0, stream>>>(qkvb, val, lsum);
  post_ln_kernel<<<2048, 256, 0, stream>>>(val, lsum, xnb, g_post, be_post, out);
}